// Round 14
// baseline (5223.556 us; speedup 1.0000x reference)
//
#include <hip/hip_runtime.h>

#define HW 4096            // 64*64
#define CIN 32

typedef __bf16 bf16x8 __attribute__((ext_vector_type(8)));
typedef float  f32x4  __attribute__((ext_vector_type(4)));
typedef unsigned short ushort8_v __attribute__((ext_vector_type(8)));

__device__ __forceinline__ unsigned short f2b(float f) {
    __bf16 b = (__bf16)f;                    // v_cvt, RNE
    return __builtin_bit_cast(unsigned short, b);
}
__device__ __forceinline__ float b2f(unsigned short s) {
    unsigned int u = ((unsigned int)s) << 16;
    return __builtin_bit_cast(float, u);
}
__device__ __forceinline__ bf16x8 ld_frag(const unsigned short* p) {
    ushort8_v u = *(const ushort8_v*)p;
    return __builtin_bit_cast(bf16x8, u);
}

// ---------- weight prep: WP[tap s][oc][ci pad 40] bf16; Tcls[oc][9] --------
__global__ __launch_bounds__(256)
void prep_kernel(const float* __restrict__ ai_w,
                 const float* __restrict__ of_w1,
                 const float* __restrict__ of_w2,
                 unsigned short* __restrict__ wp_ai,
                 unsigned short* __restrict__ wp1,
                 unsigned short* __restrict__ wp2,
                 float* __restrict__ tc1, float* __restrict__ tc2)
{
    const int t = threadIdx.x;
    for (int i = t; i < 9 * 32 * 40; i += 256) {
        const int s = i / 1280;
        const int rem = i - s * 1280;
        const int oc = rem / 40;
        const int ci = rem - oc * 40;
        unsigned short va = 0, v1 = 0, v2 = 0;
        if (ci < 32) {
            va = f2b(ai_w[(oc * 32 + ci) * 9 + s]);
            v1 = f2b(of_w1[(oc * 33 + ci + 1) * 9 + s]);
            v2 = f2b(of_w2[(oc * 33 + ci + 1) * 9 + s]);
        }
        wp_ai[i] = va; wp1[i] = v1; wp2[i] = v2;
    }
    for (int i = t; i < 32 * 9; i += 256) {
        const int oc = i / 9;
        const int cls = i - oc * 9;
        const int rc = cls / 3, cc = cls - rc * 3;
        float s1 = 0.f, s2 = 0.f;
        for (int ky = 0; ky < 3; ++ky) {
            if ((rc == 0 && ky == 0) || (rc == 2 && ky == 2)) continue;
            for (int kx = 0; kx < 3; ++kx) {
                if ((cc == 0 && kx == 0) || (cc == 2 && kx == 2)) continue;
                s1 += of_w1[(oc * 33) * 9 + ky * 3 + kx];
                s2 += of_w2[(oc * 33) * 9 + ky * 3 + kx];
            }
        }
        tc1[i] = s1; tc2[i] = s2;
    }
}

// ---------- fused prologue: y=x, YB=bf16(x), GN stats (ai_g1, of_g1) -------
__global__ __launch_bounds__(256)
void xstat_kernel(const float* __restrict__ x, float* __restrict__ y,
                  unsigned short* __restrict__ yb,
                  const float* __restrict__ g_ai, const float* __restrict__ b_ai,
                  const float* __restrict__ g_of, const float* __restrict__ b_of,
                  float* __restrict__ st_ai, float* __restrict__ st_of)
{
    const int p = blockIdx.x;          // 4096 planes (batch-128 half)
    const int c = p & 31;
    const int t = threadIdx.x;
    const float4* ip = (const float4*)(x + (size_t)p * HW);
    float4* yp = (float4*)(y + (size_t)p * HW);
    ushort4* ybp = (ushort4*)(yb + (size_t)p * HW);
    float s = 0.f, ss = 0.f;
#pragma unroll
    for (int i = 0; i < 4; ++i) {
        const float4 q = ip[t + i * 256];
        yp[t + i * 256] = q;
        ushort4 u; u.x = f2b(q.x); u.y = f2b(q.y); u.z = f2b(q.z); u.w = f2b(q.w);
        ybp[t + i * 256] = u;
        s += q.x + q.y + q.z + q.w;
        ss += q.x * q.x + q.y * q.y + q.z * q.z + q.w * q.w;
    }
#pragma unroll
    for (int off = 32; off > 0; off >>= 1) {
        s  += __shfl_xor(s, off);
        ss += __shfl_xor(ss, off);
    }
    __shared__ float red[8];
    const int wid = t >> 6;
    if ((t & 63) == 0) { red[wid] = s; red[4 + wid] = ss; }
    __syncthreads();
    if (t == 0) {
        s  = red[0] + red[1] + red[2] + red[3];
        ss = red[4] + red[5] + red[6] + red[7];
        const float mean = s * (1.f / HW);
        const float var  = ss * (1.f / HW) - mean * mean;
        const float rstd = rsqrtf(var + 1e-5f);
        const float sa = g_ai[c] * rstd;
        st_ai[p * 2]     = sa;
        st_ai[p * 2 + 1] = b_ai[c] - mean * sa;
        const float so = g_of[c] * rstd;
        st_of[p * 2]     = so;
        st_of[p * 2 + 1] = b_of[c] - mean * so;
    }
}

// ---------- MFMA implicit-GEMM conv 3x3 ------------------------------------
// 256 thr = 4 waves; block = (b, 4 output rows); tile 6x66x40 = 31.7 KB ->
// 5 blocks/CU (vs 2 at 8-row/52.8KB): cross-block overlap hides the
// stage->barrier->MFMA latency chain. Wave wid = one output row.
// FIN=0: st = per-plane (sc,sh), read directly from global during staging.
// FIN=1: st = raw partials [plane][16][2], finalized in-block into LDS.
// NOTE: no min-waves bound — wreg[2][9] needs ~88 VGPR (R12: forcing spills).
template<int HAS_TIME, int STATS, int OUT_BF16, int FIN>
__global__ __launch_bounds__(256)
void conv_kernel(const unsigned short* __restrict__ in, void* __restrict__ outv,
                 const float* __restrict__ st,
                 const float* __restrict__ fg, const float* __restrict__ fb,
                 const unsigned short* __restrict__ wp,
                 const float* __restrict__ cb, const float* __restrict__ tcls,
                 float tval, float* __restrict__ straw)
{
    const int blk = blockIdx.x;
    const int b  = blk >> 4;
    const int hb = blk & 15;
    const int h0 = hb * 4;
    const int t  = threadIdx.x;
    const int l  = t & 63;
    const int wid = t >> 6;            // 0..3 = output row
    const int lm = l & 15;
    const int lg = l >> 4;

    __shared__ unsigned short tile[6 * 66 * 40];    // 31680 B
    __shared__ float sst[64];                        // (sc,sh) per ci (FIN=1)

    // ---- GN scale/shift table (FIN=1 only: block finalize + barrier) ----
    if (FIN) {
        // st = [plane][16][2] floats = 8 float4/plane; thread t: ci=t>>3, j=t&7
        const float4 pr = ((const float4*)st)[(size_t)(b * 32 + (t >> 3)) * 8 + (t & 7)];
        float s = pr.x + pr.z, ss = pr.y + pr.w;
        s += __shfl_xor(s, 1); ss += __shfl_xor(ss, 1);
        s += __shfl_xor(s, 2); ss += __shfl_xor(ss, 2);
        s += __shfl_xor(s, 4); ss += __shfl_xor(ss, 4);
        if ((t & 7) == 0) {
            const int ci = t >> 3;
            const float mean = s * (1.f / HW);
            const float var  = ss * (1.f / HW) - mean * mean;
            const float rstd = rsqrtf(var + 1e-5f);
            const float sc = fg[ci] * rstd;
            sst[ci * 2]     = sc;
            sst[ci * 2 + 1] = fb[ci] - mean * sc;
        }
    }

    // ---- weight fragments into registers: wreg[nt][tap] ----
    bf16x8 wreg[2][9];
    {
        const unsigned short* wb = wp + (size_t)(lm * 40 + 8 * lg);
#pragma unroll
        for (int nt = 0; nt < 2; ++nt)
#pragma unroll
            for (int s = 0; s < 9; ++s)
                wreg[nt][s] = ld_frag(wb + s * 1280 + nt * 640);
    }
    if (FIN) __syncthreads();   // sst ready

    // ---- stage: 384 w-quad tasks; 8 x ushort4 loads -> 4 x ds_write_b128 --
    const unsigned short* inb = in + (size_t)b * (CIN * HW);
    const float* stb = st + (size_t)b * 64;   // FIN=0: direct (sc,sh)
#pragma unroll
    for (int tau = t; tau < 384; tau += 256) {
        const int g = tau / 96;            // channel group (8 ci)
        const int rem = tau - g * 96;
        const int r = rem >> 4;            // tile row 0..5
        const int wq = rem & 15;           // w-quad 0..15
        const int hh = h0 - 1 + r;
        unsigned short* dst = &tile[(r * 66 + wq * 4 + 1) * 40 + 8 * g];
        if (hh >= 0 && hh < 64) {
            const unsigned short* src = inb + (size_t)(8 * g) * HW + hh * 64 + wq * 4;
            ushort4 U[8];
#pragma unroll
            for (int j = 0; j < 8; ++j) U[j] = *(const ushort4*)(src + (size_t)j * HW);
            float scv[8], shv[8];
#pragma unroll
            for (int j = 0; j < 8; ++j) {
                const float2 s2 = FIN ? *(const float2*)(&sst[(8 * g + j) * 2])
                                      : *(const float2*)(stb + (8 * g + j) * 2);
                scv[j] = s2.x; shv[j] = s2.y;
            }
#pragma unroll
            for (int k = 0; k < 4; ++k) {
                ushort8_v F;
#pragma unroll
                for (int j = 0; j < 8; ++j) {
                    const unsigned short e = ((const unsigned short*)&U[j])[k];
                    F[j] = f2b(fmaxf(b2f(e) * scv[j] + shv[j], 0.f));
                }
                *(ushort8_v*)(dst + k * 40) = F;
            }
        } else {
            const ushort8_v z = {0, 0, 0, 0, 0, 0, 0, 0};
#pragma unroll
            for (int k = 0; k < 4; ++k) *(ushort8_v*)(dst + k * 40) = z;
        }
    }
    if (t < 48) {   // zero pad columns w''=0,65 (6 rows x 2 cols x 4 groups)
        const int g = t & 3;
        const int rr = t >> 2;             // 0..11
        const int r = rr >> 1;             // 0..5
        const int col = (rr & 1) ? 65 : 0;
        const ushort8_v z = {0, 0, 0, 0, 0, 0, 0, 0};
        *(ushort8_v*)&tile[(r * 66 + col) * 40 + 8 * g] = z;
    }
    __syncthreads();

    // ---- K loop: 9 taps x 4 M-tiles, weights from regs ----
    f32x4 acc[4][2];
#pragma unroll
    for (int mt = 0; mt < 4; ++mt)
#pragma unroll
        for (int nt = 0; nt < 2; ++nt) acc[mt][nt] = (f32x4){0.f, 0.f, 0.f, 0.f};

#pragma unroll
    for (int ky = 0; ky < 3; ++ky)
#pragma unroll
        for (int kx = 0; kx < 3; ++kx) {
            const int s = ky * 3 + kx;
            const int base = ((wid + ky) * 66 + kx + lm) * 40 + 8 * lg;
#pragma unroll
            for (int mt = 0; mt < 4; ++mt) {
                const bf16x8 a = ld_frag(&tile[base + mt * 640]);
                acc[mt][0] = __builtin_amdgcn_mfma_f32_16x16x32_bf16(a, wreg[0][s], acc[mt][0], 0, 0, 0);
                acc[mt][1] = __builtin_amdgcn_mfma_f32_16x16x32_bf16(a, wreg[1][s], acc[mt][1], 0, 0, 0);
            }
        }

    // ---- epilogue ----
    const int h = h0 + wid;
    const int rc = (h == 0) ? 0 : ((h == 63) ? 2 : 1);
    float bias_[2], tcn[2], tc0[2], tc2[2];
#pragma unroll
    for (int nt = 0; nt < 2; ++nt) {
        const int oc = nt * 16 + lm;
        bias_[nt] = cb[oc];
        if (HAS_TIME) {
            tcn[nt] = tcls[oc * 9 + rc * 3 + 1];
            tc0[nt] = tcls[oc * 9 + rc * 3 + 0];
            tc2[nt] = tcls[oc * 9 + rc * 3 + 2];
        }
    }
    float sl[2] = {0.f, 0.f}, ssl[2] = {0.f, 0.f};
    float* outf = (float*)outv;
    unsigned short* outb = (unsigned short*)outv;
#pragma unroll
    for (int mt = 0; mt < 4; ++mt) {
#pragma unroll
        for (int nt = 0; nt < 2; ++nt) {
            const int oc = nt * 16 + lm;
            float v[4];
#pragma unroll
            for (int r = 0; r < 4; ++r) {
                v[r] = acc[mt][nt][r] + bias_[nt];
                if (HAS_TIME) v[r] += tval * tcn[nt];
            }
            if (HAS_TIME && mt == 0 && lg == 0) v[0] += tval * (tc0[nt] - tcn[nt]);
            if (HAS_TIME && mt == 3 && lg == 3) v[3] += tval * (tc2[nt] - tcn[nt]);
            const int w0 = mt * 16 + lg * 4;
            const size_t o = ((size_t)(b * 32 + oc)) * HW + (size_t)h * 64 + w0;
            if (OUT_BF16) {
                ushort4 u;
                u.x = f2b(v[0]); u.y = f2b(v[1]); u.z = f2b(v[2]); u.w = f2b(v[3]);
                *(ushort4*)&outb[o] = u;
                if (STATS) {   // stats on rounded values (consumer reads bf16)
#pragma unroll
                    for (int r = 0; r < 4; ++r) {
                        const float vr = b2f(f2b(v[r]));
                        sl[nt] += vr; ssl[nt] += vr * vr;
                    }
                }
            } else {
                float4 q; q.x = v[0]; q.y = v[1]; q.z = v[2]; q.w = v[3];
                *(float4*)&outf[o] = q;
                if (STATS) {
#pragma unroll
                    for (int r = 0; r < 4; ++r) { sl[nt] += v[r]; ssl[nt] += v[r] * v[r]; }
                }
            }
        }
    }
    if (STATS) {
        float s0 = sl[0], q0 = ssl[0], s1 = sl[1], q1 = ssl[1];
        s0 += __shfl_xor(s0, 16); s0 += __shfl_xor(s0, 32);
        q0 += __shfl_xor(q0, 16); q0 += __shfl_xor(q0, 32);
        s1 += __shfl_xor(s1, 16); s1 += __shfl_xor(s1, 32);
        q1 += __shfl_xor(q1, 16); q1 += __shfl_xor(q1, 32);
        __syncthreads();                       // tile no longer needed
        float* red = (float*)tile;             // [0..127]=S, [128..255]=SS
        if (lg == 0) {
            red[wid * 32 + lm]       = s0;  red[128 + wid * 32 + lm]       = q0;
            red[wid * 32 + 16 + lm]  = s1;  red[128 + wid * 32 + 16 + lm]  = q1;
        }
        __syncthreads();
        if (t < 32) {
            float S = 0.f, Q = 0.f;
#pragma unroll
            for (int w = 0; w < 4; ++w) { S += red[w * 32 + t]; Q += red[128 + w * 32 + t]; }
            float* dst = straw + ((size_t)(b * 32 + t) * 16 + hb) * 2;
            dst[0] = S; dst[1] = Q;
        }
    }
}

// ---------- atten_init tail: gn2+relu -> gn3; fp32 + YB bf16 + GN1 stats ---
__global__ __launch_bounds__(256)
void dgn_kernel(const float* __restrict__ in, float* __restrict__ out,
                unsigned short* __restrict__ ybout,
                const float* __restrict__ g2, const float* __restrict__ b2,
                const float* __restrict__ g3, const float* __restrict__ b3,
                const float* __restrict__ g1n, const float* __restrict__ b1n,
                float* __restrict__ stout)
{
    const int p = blockIdx.x;
    const int c = p & 31;
    const int t = threadIdx.x;
    const float4* ip = (const float4*)(in + (size_t)p * HW);
    float4* op = (float4*)(out + (size_t)p * HW);
    ushort4* ybp = (ushort4*)(ybout + (size_t)p * HW);
    __shared__ float red[8];
    const int wid = t >> 6;

    float4 v[4];
    float s = 0.f, ss = 0.f;
#pragma unroll
    for (int i = 0; i < 4; ++i) {
        float4 q = ip[t + i * 256];
        v[i] = q;
        s += q.x + q.y + q.z + q.w;
        ss += q.x * q.x + q.y * q.y + q.z * q.z + q.w * q.w;
    }
#pragma unroll
    for (int off = 32; off > 0; off >>= 1) {
        s  += __shfl_xor(s, off);
        ss += __shfl_xor(ss, off);
    }
    if ((t & 63) == 0) { red[wid] = s; red[4 + wid] = ss; }
    __syncthreads();
    s  = red[0] + red[1] + red[2] + red[3];
    ss = red[4] + red[5] + red[6] + red[7];
    float mean = s * (1.f / HW);
    float var  = ss * (1.f / HW) - mean * mean;
    float rstd = rsqrtf(var + 1e-5f);
    float sc = g2[c] * rstd;
    float sh = b2[c] - mean * sc;

    s = 0.f; ss = 0.f;
#pragma unroll
    for (int i = 0; i < 4; ++i) {
        float4 q = v[i];
        q.x = fmaxf(q.x * sc + sh, 0.f); q.y = fmaxf(q.y * sc + sh, 0.f);
        q.z = fmaxf(q.z * sc + sh, 0.f); q.w = fmaxf(q.w * sc + sh, 0.f);
        v[i] = q;
        s += q.x + q.y + q.z + q.w;
        ss += q.x * q.x + q.y * q.y + q.z * q.z + q.w * q.w;
    }
#pragma unroll
    for (int off = 32; off > 0; off >>= 1) {
        s  += __shfl_xor(s, off);
        ss += __shfl_xor(ss, off);
    }
    __syncthreads();
    if ((t & 63) == 0) { red[wid] = s; red[4 + wid] = ss; }
    __syncthreads();
    s  = red[0] + red[1] + red[2] + red[3];
    ss = red[4] + red[5] + red[6] + red[7];
    mean = s * (1.f / HW);
    var  = ss * (1.f / HW) - mean * mean;
    rstd = rsqrtf(var + 1e-5f);
    sc = g3[c] * rstd;
    sh = b3[c] - mean * sc;

    float s3 = 0.f, ss3 = 0.f;
#pragma unroll
    for (int i = 0; i < 4; ++i) {
        float4 q = v[i];
        q.x = q.x * sc + sh; q.y = q.y * sc + sh;
        q.z = q.z * sc + sh; q.w = q.w * sc + sh;
        op[t + i * 256] = q;
        ushort4 u; u.x = f2b(q.x); u.y = f2b(q.y); u.z = f2b(q.z); u.w = f2b(q.w);
        ybp[t + i * 256] = u;
        s3 += q.x + q.y + q.z + q.w;
        ss3 += q.x * q.x + q.y * q.y + q.z * q.z + q.w * q.w;
    }
#pragma unroll
    for (int off = 32; off > 0; off >>= 1) {
        s3  += __shfl_xor(s3, off);
        ss3 += __shfl_xor(ss3, off);
    }
    __syncthreads();
    if ((t & 63) == 0) { red[wid] = s3; red[4 + wid] = ss3; }
    __syncthreads();
    if (t == 0) {
        s3  = red[0] + red[1] + red[2] + red[3];
        ss3 = red[4] + red[5] + red[6] + red[7];
        const float m3 = s3 * (1.f / HW);
        const float v3 = ss3 * (1.f / HW) - m3 * m3;
        const float r3 = rsqrtf(v3 + 1e-5f);
        const float sc1 = g1n[c] * r3;
        stout[p * 2]     = sc1;
        stout[p * 2 + 1] = b1n[c] - m3 * sc1;
    }
}

// ---------- streaming GN3 + RK update (bf16 DELTA accumulator) -------------
// kin = bf16 conv2 output; GN3 finalized in-register from 16 straw partials.
// MODE 0: D = ca*k            ; XB = bf16(yb + cy*k)
// MODE 1: D += ca*k           ; XB = bf16(yb + cy*k)
// MODE 2: y += D + ca*k (NT)  ; YB = bf16(y_new)   [no XB write; k1 reads YB]
template<int MODE>
__global__ __launch_bounds__(256)
void gnrk_kernel(const unsigned short* __restrict__ kin,
                 const float* __restrict__ straw,
                 const float* __restrict__ g, const float* __restrict__ bt,
                 float* __restrict__ y, unsigned short* __restrict__ db,
                 float ca, float cy,
                 const float* __restrict__ g1n, const float* __restrict__ b1n,
                 float* __restrict__ stout, unsigned short* __restrict__ xb,
                 unsigned short* __restrict__ yb)
{
    const int p = blockIdx.x;
    const int c = p & 31;
    const int t = threadIdx.x;

    // in-register GN3 finalize: broadcast 16 partials, 4 shuffles, no barrier
    const float2 pr = ((const float2*)straw)[(size_t)p * 16 + (t & 15)];
    float s = pr.x, ss = pr.y;
    s += __shfl_xor(s, 1); ss += __shfl_xor(ss, 1);
    s += __shfl_xor(s, 2); ss += __shfl_xor(ss, 2);
    s += __shfl_xor(s, 4); ss += __shfl_xor(ss, 4);
    s += __shfl_xor(s, 8); ss += __shfl_xor(ss, 8);
    const float mean = s * (1.f / HW);
    const float var  = ss * (1.f / HW) - mean * mean;
    const float rstd = rsqrtf(var + 1e-5f);
    const float sc = g[c] * rstd;
    const float sh = bt[c] - mean * sc;

    const ushort4* kp = (const ushort4*)(kin + (size_t)p * HW);
    const f32x4* ypl = (const f32x4*)(y + (size_t)p * HW);
    f32x4* yps = (f32x4*)(y + (size_t)p * HW);
    ushort4* dp  = (ushort4*)(db + (size_t)p * HW);
    ushort4* xp  = (ushort4*)(xb + (size_t)p * HW);
    ushort4* ybp = (ushort4*)(yb + (size_t)p * HW);
    __shared__ float red[8];
    const int wid = t >> 6;

    // ---- batch all loads first (max MLP) ----
    ushort4 ku[4];
#pragma unroll
    for (int i = 0; i < 4; ++i) ku[i] = kp[t + i * 256];
    ushort4 ybv[4];
    if (MODE != 2) {
#pragma unroll
        for (int i = 0; i < 4; ++i) ybv[i] = ybp[t + i * 256];
    }
    ushort4 dv[4];
    if (MODE != 0) {
#pragma unroll
        for (int i = 0; i < 4; ++i) dv[i] = dp[t + i * 256];
    }
    f32x4 yv[4];
    if (MODE == 2) {
#pragma unroll
        for (int i = 0; i < 4; ++i)
            yv[i] = __builtin_nontemporal_load(ypl + t + i * 256);   // NT: no alloc
    }

    float s2 = 0.f, ss2 = 0.f;
#pragma unroll
    for (int i = 0; i < 4; ++i) {
        const int idx = t + i * 256;
        f32x4 kq;
        kq[0] = b2f(ku[i].x) * sc + sh; kq[1] = b2f(ku[i].y) * sc + sh;
        kq[2] = b2f(ku[i].z) * sc + sh; kq[3] = b2f(ku[i].w) * sc + sh;
        ushort4 u;
        if (MODE != 2) {
            f32x4 d, w;
            if (MODE == 0) {
#pragma unroll
                for (int j = 0; j < 4; ++j) d[j] = ca * kq[j];
            } else {
                d[0] = b2f(dv[i].x) + ca * kq[0]; d[1] = b2f(dv[i].y) + ca * kq[1];
                d[2] = b2f(dv[i].z) + ca * kq[2]; d[3] = b2f(dv[i].w) + ca * kq[3];
            }
            w[0] = b2f(ybv[i].x) + cy * kq[0]; w[1] = b2f(ybv[i].y) + cy * kq[1];
            w[2] = b2f(ybv[i].z) + cy * kq[2]; w[3] = b2f(ybv[i].w) + cy * kq[3];
            ushort4 du;
            du.x = f2b(d[0]); du.y = f2b(d[1]); du.z = f2b(d[2]); du.w = f2b(d[3]);
            dp[idx] = du;
            u.x = f2b(w[0]); u.y = f2b(w[1]); u.z = f2b(w[2]); u.w = f2b(w[3]);
            xp[idx] = u;
        } else {
            f32x4 w;
            w[0] = yv[i][0] + b2f(dv[i].x) + ca * kq[0];
            w[1] = yv[i][1] + b2f(dv[i].y) + ca * kq[1];
            w[2] = yv[i][2] + b2f(dv[i].z) + ca * kq[2];
            w[3] = yv[i][3] + b2f(dv[i].w) + ca * kq[3];
            __builtin_nontemporal_store(w, yps + idx);
            u.x = f2b(w[0]); u.y = f2b(w[1]); u.z = f2b(w[2]); u.w = f2b(w[3]);
            ybp[idx] = u;                     // base-y shadow; k1 reads this
        }
        // GN1 stats of NEXT stage input, on rounded values (conv1 reads bf16)
        const float r0 = b2f(u.x), r1 = b2f(u.y), r2 = b2f(u.z), r3 = b2f(u.w);
        s2  += r0 + r1 + r2 + r3;
        ss2 += r0 * r0 + r1 * r1 + r2 * r2 + r3 * r3;
    }
#pragma unroll
    for (int off = 32; off > 0; off >>= 1) {
        s2  += __shfl_xor(s2, off);
        ss2 += __shfl_xor(ss2, off);
    }
    if ((t & 63) == 0) { red[wid] = s2; red[4 + wid] = ss2; }
    __syncthreads();
    if (t == 0) {
        s2  = red[0] + red[1] + red[2] + red[3];
        ss2 = red[4] + red[5] + red[6] + red[7];
        const float m2 = s2 * (1.f / HW);
        const float v2 = ss2 * (1.f / HW) - m2 * m2;
        const float r2 = rsqrtf(v2 + 1e-5f);
        const float sc1 = g1n[c] * r2;
        stout[p * 2]     = sc1;
        stout[p * 2 + 1] = b1n[c] - m2 * sc1;
    }
}

extern "C" void kernel_launch(void* const* d_in, const int* in_sizes, int n_in,
                              void* d_out, int out_size, void* d_ws, size_t ws_size,
                              hipStream_t stream) {
    (void)in_sizes; (void)n_in; (void)out_size; (void)ws_size;
    const float* x      = (const float*)d_in[0];
    const float* ai_g1  = (const float*)d_in[1];
    const float* ai_b1  = (const float*)d_in[2];
    const float* ai_w   = (const float*)d_in[3];
    const float* ai_cb  = (const float*)d_in[4];
    const float* ai_g2  = (const float*)d_in[5];
    const float* ai_b2  = (const float*)d_in[6];
    const float* ai_g3  = (const float*)d_in[7];
    const float* ai_b3  = (const float*)d_in[8];
    const float* of_g1  = (const float*)d_in[9];
    const float* of_b1  = (const float*)d_in[10];
    const float* of_w1  = (const float*)d_in[11];
    const float* of_cb1 = (const float*)d_in[12];
    const float* of_g2  = (const float*)d_in[13];
    const float* of_b2  = (const float*)d_in[14];
    const float* of_w2  = (const float*)d_in[15];
    const float* of_cb2 = (const float*)d_in[16];
    const float* of_g3  = (const float*)d_in[17];
    const float* of_b3  = (const float*)d_in[18];

    float* y = (float*)d_out;                         // (256,32,64,64) fp32
    const size_t N  = (size_t)256 * 32 * 64 * 64;
    const size_t NH = N / 2;
    float* ws = (float*)d_ws;
    unsigned short* DB  = (unsigned short*)ws;                   // RK delta bf16 (N)
    float* YTf = ws;                                             // prologue alias (NH f)
    unsigned short* YB  = (unsigned short*)(ws + N / 2);         // bf16 y-shadow
    unsigned short* Abf = (unsigned short*)(ws + N);             // conv1 out bf16
    unsigned short* XB  = (unsigned short*)(ws + N + N / 2);     // stage in bf16
    unsigned short* YTB = (unsigned short*)(ws + 2 * N);         // conv2 out bf16
    float* tail  = ws + 2 * N + N / 2;
    float* ST1    = tail;               tail += 16384;   // GN1 (sc,sh), 8192 pl
    float* ST_AI  = tail;               tail += 8192;
    float* STRAW1 = tail;               tail += 262144;  // conv1 partials [pl][16][2]
    float* STRAW2 = tail;               tail += 262144;  // conv2 partials
    unsigned short* WPai = (unsigned short*)tail;  tail += 5760;
    unsigned short* WP1  = (unsigned short*)tail;  tail += 5760;
    unsigned short* WP2  = (unsigned short*)tail;  tail += 5760;
    float* TC1  = tail;                 tail += 288;
    float* TC2  = tail;                 tail += 288;

    const float h = 0.125f;

    prep_kernel<<<1, 256, 0, stream>>>(ai_w, of_w1, of_w2, WPai, WP1, WP2, TC1, TC2);

    // ---- atten_init (batch 128): fused y=x / YB / both stat sets ----
    xstat_kernel<<<4096, 256, 0, stream>>>(x, y, YB, ai_g1, ai_b1, of_g1, of_b1,
                                           ST_AI, ST1);
    conv_kernel<0, 0, 0, 0><<<2048, 256, 0, stream>>>(YB, YTf, ST_AI, nullptr, nullptr,
                                                      WPai, ai_cb, nullptr, 0.f, nullptr);
    dgn_kernel<<<4096, 256, 0, stream>>>(YTf, y + NH, YB + NH, ai_g2, ai_b2,
                                         ai_g3, ai_b3, of_g1, of_b1, ST1 + 8192);

    // stage-input selector: k1 reads YB (written by mode 2 / prologue),
    // k2..k4 read XB (written by modes 0/1).
    auto eval = [&](const unsigned short* sin, float tv, float ca, float cy, int mode) {
        conv_kernel<1, 1, 1, 0><<<4096, 256, 0, stream>>>(sin, Abf, ST1, nullptr, nullptr,
                                                          WP1, of_cb1, TC1, tv, STRAW1);
        conv_kernel<1, 1, 1, 1><<<4096, 256, 0, stream>>>(Abf, YTB, STRAW1, of_g2, of_b2,
                                                          WP2, of_cb2, TC2, tv, STRAW2);
        if (mode == 0)
            gnrk_kernel<0><<<8192, 256, 0, stream>>>(YTB, STRAW2, of_g3, of_b3, y, DB,
                                                     ca, cy, of_g1, of_b1, ST1, XB, YB);
        else if (mode == 1)
            gnrk_kernel<1><<<8192, 256, 0, stream>>>(YTB, STRAW2, of_g3, of_b3, y, DB,
                                                     ca, cy, of_g1, of_b1, ST1, XB, YB);
        else
            gnrk_kernel<2><<<8192, 256, 0, stream>>>(YTB, STRAW2, of_g3, of_b3, y, DB,
                                                     ca, cy, of_g1, of_b1, ST1, XB, YB);
    };

    for (int s = 0; s < 8; ++s) {
        const float t0 = h * (float)s;
        eval(YB, t0,            h / 6.f, 0.5f * h, 0);   // k1
        eval(XB, t0 + 0.5f * h, h / 3.f, 0.5f * h, 1);   // k2
        eval(XB, t0 + 0.5f * h, h / 3.f, h,        1);   // k3
        eval(XB, t0 + h,        h / 6.f, 0.f,      2);   // k4
    }
}

// Round 15
// 4836.687 us; speedup vs baseline: 1.0800x; 1.0800x over previous
//
#include <hip/hip_runtime.h>

#define HW 4096            // 64*64
#define CIN 32

typedef __bf16 bf16x8 __attribute__((ext_vector_type(8)));
typedef float  f32x4  __attribute__((ext_vector_type(4)));
typedef unsigned short ushort8_v __attribute__((ext_vector_type(8)));

__device__ __forceinline__ unsigned short f2b(float f) {
    __bf16 b = (__bf16)f;                    // v_cvt, RNE
    return __builtin_bit_cast(unsigned short, b);
}
__device__ __forceinline__ float b2f(unsigned short s) {
    unsigned int u = ((unsigned int)s) << 16;
    return __builtin_bit_cast(float, u);
}
__device__ __forceinline__ bf16x8 ld_frag(const unsigned short* p) {
    ushort8_v u = *(const ushort8_v*)p;
    return __builtin_bit_cast(bf16x8, u);
}

// ---------- weight prep: WP[tap s][oc][ci pad 40] bf16; Tcls[oc][9] --------
__global__ __launch_bounds__(256)
void prep_kernel(const float* __restrict__ ai_w,
                 const float* __restrict__ of_w1,
                 const float* __restrict__ of_w2,
                 unsigned short* __restrict__ wp_ai,
                 unsigned short* __restrict__ wp1,
                 unsigned short* __restrict__ wp2,
                 float* __restrict__ tc1, float* __restrict__ tc2)
{
    const int t = threadIdx.x;
    for (int i = t; i < 9 * 32 * 40; i += 256) {
        const int s = i / 1280;
        const int rem = i - s * 1280;
        const int oc = rem / 40;
        const int ci = rem - oc * 40;
        unsigned short va = 0, v1 = 0, v2 = 0;
        if (ci < 32) {
            va = f2b(ai_w[(oc * 32 + ci) * 9 + s]);
            v1 = f2b(of_w1[(oc * 33 + ci + 1) * 9 + s]);
            v2 = f2b(of_w2[(oc * 33 + ci + 1) * 9 + s]);
        }
        wp_ai[i] = va; wp1[i] = v1; wp2[i] = v2;
    }
    for (int i = t; i < 32 * 9; i += 256) {
        const int oc = i / 9;
        const int cls = i - oc * 9;
        const int rc = cls / 3, cc = cls - rc * 3;
        float s1 = 0.f, s2 = 0.f;
        for (int ky = 0; ky < 3; ++ky) {
            if ((rc == 0 && ky == 0) || (rc == 2 && ky == 2)) continue;
            for (int kx = 0; kx < 3; ++kx) {
                if ((cc == 0 && kx == 0) || (cc == 2 && kx == 2)) continue;
                s1 += of_w1[(oc * 33) * 9 + ky * 3 + kx];
                s2 += of_w2[(oc * 33) * 9 + ky * 3 + kx];
            }
        }
        tc1[i] = s1; tc2[i] = s2;
    }
}

// ---------- fused prologue: y=x, YB=bf16(x), GN stats (ai_g1, of_g1) -------
__global__ __launch_bounds__(256)
void xstat_kernel(const float* __restrict__ x, float* __restrict__ y,
                  unsigned short* __restrict__ yb,
                  const float* __restrict__ g_ai, const float* __restrict__ b_ai,
                  const float* __restrict__ g_of, const float* __restrict__ b_of,
                  float* __restrict__ st_ai, float* __restrict__ st_of)
{
    const int p = blockIdx.x;          // 4096 planes (batch-128 half)
    const int c = p & 31;
    const int t = threadIdx.x;
    const float4* ip = (const float4*)(x + (size_t)p * HW);
    float4* yp = (float4*)(y + (size_t)p * HW);
    ushort4* ybp = (ushort4*)(yb + (size_t)p * HW);
    float s = 0.f, ss = 0.f;
#pragma unroll
    for (int i = 0; i < 4; ++i) {
        const float4 q = ip[t + i * 256];
        yp[t + i * 256] = q;
        ushort4 u; u.x = f2b(q.x); u.y = f2b(q.y); u.z = f2b(q.z); u.w = f2b(q.w);
        ybp[t + i * 256] = u;
        s += q.x + q.y + q.z + q.w;
        ss += q.x * q.x + q.y * q.y + q.z * q.z + q.w * q.w;
    }
#pragma unroll
    for (int off = 32; off > 0; off >>= 1) {
        s  += __shfl_xor(s, off);
        ss += __shfl_xor(ss, off);
    }
    __shared__ float red[8];
    const int wid = t >> 6;
    if ((t & 63) == 0) { red[wid] = s; red[4 + wid] = ss; }
    __syncthreads();
    if (t == 0) {
        s  = red[0] + red[1] + red[2] + red[3];
        ss = red[4] + red[5] + red[6] + red[7];
        const float mean = s * (1.f / HW);
        const float var  = ss * (1.f / HW) - mean * mean;
        const float rstd = rsqrtf(var + 1e-5f);
        const float sa = g_ai[c] * rstd;
        st_ai[p * 2]     = sa;
        st_ai[p * 2 + 1] = b_ai[c] - mean * sa;
        const float so = g_of[c] * rstd;
        st_of[p * 2]     = so;
        st_of[p * 2 + 1] = b_of[c] - mean * so;
    }
}

// ---------- MFMA implicit-GEMM conv 3x3 ------------------------------------
// 512 thr = 8 waves; block = (b, 8 output rows). Wave wid = one row of 64 px.
// K loop split over nt (oc half): wreg[9] (36 VGPR) per half instead of
// wreg[2][9] (72) -> peak live ~80 VGPR -> 6 waves/SIMD -> 3 blocks/CU
// (LDS 3x52.8=158.4KB fits). A-fragments re-read per half (LDS pipe has
// headroom). NO launch-bound forcing (R12: forcing spills weights).
template<int HAS_TIME, int STATS, int OUT_BF16, int FIN>
__global__ __launch_bounds__(512)
void conv_kernel(const unsigned short* __restrict__ in, void* __restrict__ outv,
                 const float* __restrict__ st,
                 const float* __restrict__ fg, const float* __restrict__ fb,
                 const unsigned short* __restrict__ wp,
                 const float* __restrict__ cb, const float* __restrict__ tcls,
                 float tval, float* __restrict__ straw)
{
    const int blk = blockIdx.x;
    const int b  = blk >> 3;
    const int hb = blk & 7;
    const int h0 = hb * 8;
    const int t  = threadIdx.x;
    const int l  = t & 63;
    const int wid = t >> 6;            // 0..7 = output row
    const int lm = l & 15;
    const int lg = l >> 4;

    __shared__ unsigned short tile[10 * 66 * 40];   // 52800 B
    __shared__ float sst[64];                        // (sc,sh) per ci (FIN=1)

    // ---- GN scale/shift table (FIN=1 only: block finalize + barrier) ----
    if (FIN) {
        float s = 0.f, ss = 0.f;
        if (t < 256) {
            const float2 pr = ((const float2*)st)[(size_t)(b * 32 + (t >> 3)) * 8 + (t & 7)];
            s = pr.x; ss = pr.y;
        }
        s += __shfl_xor(s, 1); ss += __shfl_xor(ss, 1);
        s += __shfl_xor(s, 2); ss += __shfl_xor(ss, 2);
        s += __shfl_xor(s, 4); ss += __shfl_xor(ss, 4);
        if (t < 256 && (t & 7) == 0) {
            const int ci = t >> 3;
            const float mean = s * (1.f / HW);
            const float var  = ss * (1.f / HW) - mean * mean;
            const float rstd = rsqrtf(var + 1e-5f);
            const float sc = fg[ci] * rstd;
            sst[ci * 2]     = sc;
            sst[ci * 2 + 1] = fb[ci] - mean * sc;
        }
        __syncthreads();   // sst ready
    }

    // ---- stage: 640 w-quad tasks; 8 x ushort4 loads -> 4 x ds_write_b128 --
    const unsigned short* inb = in + (size_t)b * (CIN * HW);
    const float* stb = st + (size_t)b * 64;   // FIN=0: direct (sc,sh)
#pragma unroll
    for (int tau = t; tau < 640; tau += 512) {
        const int g = tau / 160;           // channel group (8 ci)
        const int rem = tau - g * 160;
        const int r = rem >> 4;            // tile row 0..9
        const int wq = rem & 15;           // w-quad 0..15
        const int hh = h0 - 1 + r;
        unsigned short* dst = &tile[(r * 66 + wq * 4 + 1) * 40 + 8 * g];
        if (hh >= 0 && hh < 64) {
            const unsigned short* src = inb + (size_t)(8 * g) * HW + hh * 64 + wq * 4;
            ushort4 U[8];
#pragma unroll
            for (int j = 0; j < 8; ++j) U[j] = *(const ushort4*)(src + (size_t)j * HW);
            float scv[8], shv[8];
#pragma unroll
            for (int j = 0; j < 8; ++j) {
                const float2 s2 = FIN ? *(const float2*)(&sst[(8 * g + j) * 2])
                                      : *(const float2*)(stb + (8 * g + j) * 2);
                scv[j] = s2.x; shv[j] = s2.y;
            }
#pragma unroll
            for (int k = 0; k < 4; ++k) {
                ushort8_v F;
#pragma unroll
                for (int j = 0; j < 8; ++j) {
                    const unsigned short e = ((const unsigned short*)&U[j])[k];
                    F[j] = f2b(fmaxf(b2f(e) * scv[j] + shv[j], 0.f));
                }
                *(ushort8_v*)(dst + k * 40) = F;
            }
        } else {
            const ushort8_v z = {0, 0, 0, 0, 0, 0, 0, 0};
#pragma unroll
            for (int k = 0; k < 4; ++k) *(ushort8_v*)(dst + k * 40) = z;
        }
    }
    if (t < 80) {   // zero pad columns w''=0,65
        const int g = t & 3;
        const int rr = t >> 2;
        const int r = rr >> 1;
        const int col = (rr & 1) ? 65 : 0;
        const ushort8_v z = {0, 0, 0, 0, 0, 0, 0, 0};
        *(ushort8_v*)&tile[(r * 66 + col) * 40 + 8 * g] = z;
    }
    __syncthreads();

    // ---- K loop: nt outer (wreg[9] live per half), 9 taps x 4 M-tiles ----
    f32x4 acc[4][2];
#pragma unroll
    for (int mt = 0; mt < 4; ++mt)
#pragma unroll
        for (int nt = 0; nt < 2; ++nt) acc[mt][nt] = (f32x4){0.f, 0.f, 0.f, 0.f};

#pragma unroll
    for (int nt = 0; nt < 2; ++nt) {
        bf16x8 wreg[9];
        {
            const unsigned short* wb = wp + (size_t)(lm * 40 + 8 * lg + nt * 640);
#pragma unroll
            for (int s = 0; s < 9; ++s) wreg[s] = ld_frag(wb + s * 1280);
        }
#pragma unroll
        for (int ky = 0; ky < 3; ++ky)
#pragma unroll
            for (int kx = 0; kx < 3; ++kx) {
                const int s = ky * 3 + kx;
                const int base = ((wid + ky) * 66 + kx + lm) * 40 + 8 * lg;
#pragma unroll
                for (int mt = 0; mt < 4; ++mt) {
                    const bf16x8 a = ld_frag(&tile[base + mt * 640]);
                    acc[mt][nt] = __builtin_amdgcn_mfma_f32_16x16x32_bf16(a, wreg[s], acc[mt][nt], 0, 0, 0);
                }
            }
    }

    // ---- epilogue ----
    const int h = h0 + wid;
    const int rc = (h == 0) ? 0 : ((h == 63) ? 2 : 1);
    float bias_[2], tcn[2], tc0[2], tc2[2];
#pragma unroll
    for (int nt = 0; nt < 2; ++nt) {
        const int oc = nt * 16 + lm;
        bias_[nt] = cb[oc];
        if (HAS_TIME) {
            tcn[nt] = tcls[oc * 9 + rc * 3 + 1];
            tc0[nt] = tcls[oc * 9 + rc * 3 + 0];
            tc2[nt] = tcls[oc * 9 + rc * 3 + 2];
        }
    }
    float sl[2] = {0.f, 0.f}, ssl[2] = {0.f, 0.f};
    float* outf = (float*)outv;
    unsigned short* outb = (unsigned short*)outv;
#pragma unroll
    for (int mt = 0; mt < 4; ++mt) {
#pragma unroll
        for (int nt = 0; nt < 2; ++nt) {
            const int oc = nt * 16 + lm;
            float v[4];
#pragma unroll
            for (int r = 0; r < 4; ++r) {
                v[r] = acc[mt][nt][r] + bias_[nt];
                if (HAS_TIME) v[r] += tval * tcn[nt];
            }
            if (HAS_TIME && mt == 0 && lg == 0) v[0] += tval * (tc0[nt] - tcn[nt]);
            if (HAS_TIME && mt == 3 && lg == 3) v[3] += tval * (tc2[nt] - tcn[nt]);
            const int w0 = mt * 16 + lg * 4;
            const size_t o = ((size_t)(b * 32 + oc)) * HW + (size_t)h * 64 + w0;
            if (OUT_BF16) {
                ushort4 u;
                u.x = f2b(v[0]); u.y = f2b(v[1]); u.z = f2b(v[2]); u.w = f2b(v[3]);
                *(ushort4*)&outb[o] = u;
                if (STATS) {   // stats on rounded values (consumer reads bf16)
#pragma unroll
                    for (int r = 0; r < 4; ++r) {
                        const float vr = b2f(f2b(v[r]));
                        sl[nt] += vr; ssl[nt] += vr * vr;
                    }
                }
            } else {
                float4 q; q.x = v[0]; q.y = v[1]; q.z = v[2]; q.w = v[3];
                *(float4*)&outf[o] = q;
                if (STATS) {
#pragma unroll
                    for (int r = 0; r < 4; ++r) { sl[nt] += v[r]; ssl[nt] += v[r] * v[r]; }
                }
            }
        }
    }
    if (STATS) {
        float s0 = sl[0], q0 = ssl[0], s1 = sl[1], q1 = ssl[1];
        s0 += __shfl_xor(s0, 16); s0 += __shfl_xor(s0, 32);
        q0 += __shfl_xor(q0, 16); q0 += __shfl_xor(q0, 32);
        s1 += __shfl_xor(s1, 16); s1 += __shfl_xor(s1, 32);
        q1 += __shfl_xor(q1, 16); q1 += __shfl_xor(q1, 32);
        __syncthreads();                       // tile no longer needed
        float* red = (float*)tile;             // [0..255]=S, [256..511]=SS
        if (lg == 0) {
            red[wid * 32 + lm]       = s0;  red[256 + wid * 32 + lm]       = q0;
            red[wid * 32 + 16 + lm]  = s1;  red[256 + wid * 32 + 16 + lm]  = q1;
        }
        __syncthreads();
        if (t < 32) {
            float S = 0.f, Q = 0.f;
#pragma unroll
            for (int w = 0; w < 8; ++w) { S += red[w * 32 + t]; Q += red[256 + w * 32 + t]; }
            float* dst = straw + ((size_t)(b * 32 + t) * 8 + hb) * 2;
            dst[0] = S; dst[1] = Q;
        }
    }
}

// ---------- atten_init tail: gn2+relu -> gn3; fp32 + YB bf16 + GN1 stats ---
__global__ __launch_bounds__(256)
void dgn_kernel(const float* __restrict__ in, float* __restrict__ out,
                unsigned short* __restrict__ ybout,
                const float* __restrict__ g2, const float* __restrict__ b2,
                const float* __restrict__ g3, const float* __restrict__ b3,
                const float* __restrict__ g1n, const float* __restrict__ b1n,
                float* __restrict__ stout)
{
    const int p = blockIdx.x;
    const int c = p & 31;
    const int t = threadIdx.x;
    const float4* ip = (const float4*)(in + (size_t)p * HW);
    float4* op = (float4*)(out + (size_t)p * HW);
    ushort4* ybp = (ushort4*)(ybout + (size_t)p * HW);
    __shared__ float red[8];
    const int wid = t >> 6;

    float4 v[4];
    float s = 0.f, ss = 0.f;
#pragma unroll
    for (int i = 0; i < 4; ++i) {
        float4 q = ip[t + i * 256];
        v[i] = q;
        s += q.x + q.y + q.z + q.w;
        ss += q.x * q.x + q.y * q.y + q.z * q.z + q.w * q.w;
    }
#pragma unroll
    for (int off = 32; off > 0; off >>= 1) {
        s  += __shfl_xor(s, off);
        ss += __shfl_xor(ss, off);
    }
    if ((t & 63) == 0) { red[wid] = s; red[4 + wid] = ss; }
    __syncthreads();
    s  = red[0] + red[1] + red[2] + red[3];
    ss = red[4] + red[5] + red[6] + red[7];
    float mean = s * (1.f / HW);
    float var  = ss * (1.f / HW) - mean * mean;
    float rstd = rsqrtf(var + 1e-5f);
    float sc = g2[c] * rstd;
    float sh = b2[c] - mean * sc;

    s = 0.f; ss = 0.f;
#pragma unroll
    for (int i = 0; i < 4; ++i) {
        float4 q = v[i];
        q.x = fmaxf(q.x * sc + sh, 0.f); q.y = fmaxf(q.y * sc + sh, 0.f);
        q.z = fmaxf(q.z * sc + sh, 0.f); q.w = fmaxf(q.w * sc + sh, 0.f);
        v[i] = q;
        s += q.x + q.y + q.z + q.w;
        ss += q.x * q.x + q.y * q.y + q.z * q.z + q.w * q.w;
    }
#pragma unroll
    for (int off = 32; off > 0; off >>= 1) {
        s  += __shfl_xor(s, off);
        ss += __shfl_xor(ss, off);
    }
    __syncthreads();
    if ((t & 63) == 0) { red[wid] = s; red[4 + wid] = ss; }
    __syncthreads();
    s  = red[0] + red[1] + red[2] + red[3];
    ss = red[4] + red[5] + red[6] + red[7];
    mean = s * (1.f / HW);
    var  = ss * (1.f / HW) - mean * mean;
    rstd = rsqrtf(var + 1e-5f);
    sc = g3[c] * rstd;
    sh = b3[c] - mean * sc;

    float s3 = 0.f, ss3 = 0.f;
#pragma unroll
    for (int i = 0; i < 4; ++i) {
        float4 q = v[i];
        q.x = q.x * sc + sh; q.y = q.y * sc + sh;
        q.z = q.z * sc + sh; q.w = q.w * sc + sh;
        op[t + i * 256] = q;
        ushort4 u; u.x = f2b(q.x); u.y = f2b(q.y); u.z = f2b(q.z); u.w = f2b(q.w);
        ybp[t + i * 256] = u;
        s3 += q.x + q.y + q.z + q.w;
        ss3 += q.x * q.x + q.y * q.y + q.z * q.z + q.w * q.w;
    }
#pragma unroll
    for (int off = 32; off > 0; off >>= 1) {
        s3  += __shfl_xor(s3, off);
        ss3 += __shfl_xor(ss3, off);
    }
    __syncthreads();
    if ((t & 63) == 0) { red[wid] = s3; red[4 + wid] = ss3; }
    __syncthreads();
    if (t == 0) {
        s3  = red[0] + red[1] + red[2] + red[3];
        ss3 = red[4] + red[5] + red[6] + red[7];
        const float m3 = s3 * (1.f / HW);
        const float v3 = ss3 * (1.f / HW) - m3 * m3;
        const float r3 = rsqrtf(v3 + 1e-5f);
        const float sc1 = g1n[c] * r3;
        stout[p * 2]     = sc1;
        stout[p * 2 + 1] = b1n[c] - m3 * sc1;
    }
}

// ---------- streaming GN3 + RK update (bf16 DELTA accumulator) -------------
// kin = bf16 conv2 output; GN3 finalized in-register from straw (no barrier).
// MODE 0: D = ca*k            ; XB = bf16(yb + cy*k)
// MODE 1: D += ca*k           ; XB = bf16(yb + cy*k)
// MODE 2: y += D + ca*k (NT)  ; YB = bf16(y_new)   [no XB write; k1 reads YB]
template<int MODE>
__global__ __launch_bounds__(256)
void gnrk_kernel(const unsigned short* __restrict__ kin,
                 const float* __restrict__ straw,
                 const float* __restrict__ g, const float* __restrict__ bt,
                 float* __restrict__ y, unsigned short* __restrict__ db,
                 float ca, float cy,
                 const float* __restrict__ g1n, const float* __restrict__ b1n,
                 float* __restrict__ stout, unsigned short* __restrict__ xb,
                 unsigned short* __restrict__ yb)
{
    const int p = blockIdx.x;
    const int c = p & 31;
    const int t = threadIdx.x;

    // in-register GN3 finalize: broadcast 8 partials, 3 shuffles, no barrier
    const float2 pr = ((const float2*)straw)[(size_t)p * 8 + (t & 7)];
    float s = pr.x, ss = pr.y;
    s += __shfl_xor(s, 1); ss += __shfl_xor(ss, 1);
    s += __shfl_xor(s, 2); ss += __shfl_xor(ss, 2);
    s += __shfl_xor(s, 4); ss += __shfl_xor(ss, 4);
    const float mean = s * (1.f / HW);
    const float var  = ss * (1.f / HW) - mean * mean;
    const float rstd = rsqrtf(var + 1e-5f);
    const float sc = g[c] * rstd;
    const float sh = bt[c] - mean * sc;

    const ushort4* kp = (const ushort4*)(kin + (size_t)p * HW);
    const f32x4* ypl = (const f32x4*)(y + (size_t)p * HW);
    f32x4* yps = (f32x4*)(y + (size_t)p * HW);
    ushort4* dp  = (ushort4*)(db + (size_t)p * HW);
    ushort4* xp  = (ushort4*)(xb + (size_t)p * HW);
    ushort4* ybp = (ushort4*)(yb + (size_t)p * HW);
    __shared__ float red[8];
    const int wid = t >> 6;

    // ---- batch all loads first (max MLP) ----
    ushort4 ku[4];
#pragma unroll
    for (int i = 0; i < 4; ++i) ku[i] = kp[t + i * 256];
    ushort4 ybv[4];
    if (MODE != 2) {
#pragma unroll
        for (int i = 0; i < 4; ++i) ybv[i] = ybp[t + i * 256];
    }
    ushort4 dv[4];
    if (MODE != 0) {
#pragma unroll
        for (int i = 0; i < 4; ++i) dv[i] = dp[t + i * 256];
    }
    f32x4 yv[4];
    if (MODE == 2) {
#pragma unroll
        for (int i = 0; i < 4; ++i)
            yv[i] = __builtin_nontemporal_load(ypl + t + i * 256);   // NT: no alloc
    }

    float s2 = 0.f, ss2 = 0.f;
#pragma unroll
    for (int i = 0; i < 4; ++i) {
        const int idx = t + i * 256;
        f32x4 kq;
        kq[0] = b2f(ku[i].x) * sc + sh; kq[1] = b2f(ku[i].y) * sc + sh;
        kq[2] = b2f(ku[i].z) * sc + sh; kq[3] = b2f(ku[i].w) * sc + sh;
        ushort4 u;
        if (MODE != 2) {
            f32x4 d, w;
            if (MODE == 0) {
#pragma unroll
                for (int j = 0; j < 4; ++j) d[j] = ca * kq[j];
            } else {
                d[0] = b2f(dv[i].x) + ca * kq[0]; d[1] = b2f(dv[i].y) + ca * kq[1];
                d[2] = b2f(dv[i].z) + ca * kq[2]; d[3] = b2f(dv[i].w) + ca * kq[3];
            }
            w[0] = b2f(ybv[i].x) + cy * kq[0]; w[1] = b2f(ybv[i].y) + cy * kq[1];
            w[2] = b2f(ybv[i].z) + cy * kq[2]; w[3] = b2f(ybv[i].w) + cy * kq[3];
            ushort4 du;
            du.x = f2b(d[0]); du.y = f2b(d[1]); du.z = f2b(d[2]); du.w = f2b(d[3]);
            dp[idx] = du;
            u.x = f2b(w[0]); u.y = f2b(w[1]); u.z = f2b(w[2]); u.w = f2b(w[3]);
            xp[idx] = u;
        } else {
            f32x4 w;
            w[0] = yv[i][0] + b2f(dv[i].x) + ca * kq[0];
            w[1] = yv[i][1] + b2f(dv[i].y) + ca * kq[1];
            w[2] = yv[i][2] + b2f(dv[i].z) + ca * kq[2];
            w[3] = yv[i][3] + b2f(dv[i].w) + ca * kq[3];
            __builtin_nontemporal_store(w, yps + idx);
            u.x = f2b(w[0]); u.y = f2b(w[1]); u.z = f2b(w[2]); u.w = f2b(w[3]);
            ybp[idx] = u;                     // base-y shadow; k1 reads this
        }
        // GN1 stats of NEXT stage input, on rounded values (conv1 reads bf16)
        const float r0 = b2f(u.x), r1 = b2f(u.y), r2 = b2f(u.z), r3 = b2f(u.w);
        s2  += r0 + r1 + r2 + r3;
        ss2 += r0 * r0 + r1 * r1 + r2 * r2 + r3 * r3;
    }
#pragma unroll
    for (int off = 32; off > 0; off >>= 1) {
        s2  += __shfl_xor(s2, off);
        ss2 += __shfl_xor(ss2, off);
    }
    if ((t & 63) == 0) { red[wid] = s2; red[4 + wid] = ss2; }
    __syncthreads();
    if (t == 0) {
        s2  = red[0] + red[1] + red[2] + red[3];
        ss2 = red[4] + red[5] + red[6] + red[7];
        const float m2 = s2 * (1.f / HW);
        const float v2 = ss2 * (1.f / HW) - m2 * m2;
        const float r2 = rsqrtf(v2 + 1e-5f);
        const float sc1 = g1n[c] * r2;
        stout[p * 2]     = sc1;
        stout[p * 2 + 1] = b1n[c] - m2 * sc1;
    }
}

extern "C" void kernel_launch(void* const* d_in, const int* in_sizes, int n_in,
                              void* d_out, int out_size, void* d_ws, size_t ws_size,
                              hipStream_t stream) {
    (void)in_sizes; (void)n_in; (void)out_size; (void)ws_size;
    const float* x      = (const float*)d_in[0];
    const float* ai_g1  = (const float*)d_in[1];
    const float* ai_b1  = (const float*)d_in[2];
    const float* ai_w   = (const float*)d_in[3];
    const float* ai_cb  = (const float*)d_in[4];
    const float* ai_g2  = (const float*)d_in[5];
    const float* ai_b2  = (const float*)d_in[6];
    const float* ai_g3  = (const float*)d_in[7];
    const float* ai_b3  = (const float*)d_in[8];
    const float* of_g1  = (const float*)d_in[9];
    const float* of_b1  = (const float*)d_in[10];
    const float* of_w1  = (const float*)d_in[11];
    const float* of_cb1 = (const float*)d_in[12];
    const float* of_g2  = (const float*)d_in[13];
    const float* of_b2  = (const float*)d_in[14];
    const float* of_w2  = (const float*)d_in[15];
    const float* of_cb2 = (const float*)d_in[16];
    const float* of_g3  = (const float*)d_in[17];
    const float* of_b3  = (const float*)d_in[18];

    float* y = (float*)d_out;                         // (256,32,64,64) fp32
    const size_t N  = (size_t)256 * 32 * 64 * 64;
    const size_t NH = N / 2;
    float* ws = (float*)d_ws;
    unsigned short* DB  = (unsigned short*)ws;                   // RK delta bf16 (N)
    float* YTf = ws;                                             // prologue alias (NH f)
    unsigned short* YB  = (unsigned short*)(ws + N / 2);         // bf16 y-shadow
    unsigned short* Abf = (unsigned short*)(ws + N);             // conv1 out bf16
    unsigned short* XB  = (unsigned short*)(ws + N + N / 2);     // stage in bf16
    unsigned short* YTB = (unsigned short*)(ws + 2 * N);         // conv2 out bf16
    float* tail  = ws + 2 * N + N / 2;
    float* ST1    = tail;               tail += 16384;   // GN1 (sc,sh), 8192 pl
    float* ST_AI  = tail;               tail += 8192;
    float* STRAW1 = tail;               tail += 131072;  // conv1 partials [pl][8][2]
    float* STRAW2 = tail;               tail += 131072;  // conv2 partials
    unsigned short* WPai = (unsigned short*)tail;  tail += 5760;
    unsigned short* WP1  = (unsigned short*)tail;  tail += 5760;
    unsigned short* WP2  = (unsigned short*)tail;  tail += 5760;
    float* TC1  = tail;                 tail += 288;
    float* TC2  = tail;                 tail += 288;

    const float h = 0.125f;

    prep_kernel<<<1, 256, 0, stream>>>(ai_w, of_w1, of_w2, WPai, WP1, WP2, TC1, TC2);

    // ---- atten_init (batch 128): fused y=x / YB / both stat sets ----
    xstat_kernel<<<4096, 256, 0, stream>>>(x, y, YB, ai_g1, ai_b1, of_g1, of_b1,
                                           ST_AI, ST1);
    conv_kernel<0, 0, 0, 0><<<1024, 512, 0, stream>>>(YB, YTf, ST_AI, nullptr, nullptr,
                                                      WPai, ai_cb, nullptr, 0.f, nullptr);
    dgn_kernel<<<4096, 256, 0, stream>>>(YTf, y + NH, YB + NH, ai_g2, ai_b2,
                                         ai_g3, ai_b3, of_g1, of_b1, ST1 + 8192);

    // stage-input selector: k1 reads YB (written by mode 2 / prologue),
    // k2..k4 read XB (written by modes 0/1).
    auto eval = [&](const unsigned short* sin, float tv, float ca, float cy, int mode) {
        conv_kernel<1, 1, 1, 0><<<2048, 512, 0, stream>>>(sin, Abf, ST1, nullptr, nullptr,
                                                          WP1, of_cb1, TC1, tv, STRAW1);
        conv_kernel<1, 1, 1, 1><<<2048, 512, 0, stream>>>(Abf, YTB, STRAW1, of_g2, of_b2,
                                                          WP2, of_cb2, TC2, tv, STRAW2);
        if (mode == 0)
            gnrk_kernel<0><<<8192, 256, 0, stream>>>(YTB, STRAW2, of_g3, of_b3, y, DB,
                                                     ca, cy, of_g1, of_b1, ST1, XB, YB);
        else if (mode == 1)
            gnrk_kernel<1><<<8192, 256, 0, stream>>>(YTB, STRAW2, of_g3, of_b3, y, DB,
                                                     ca, cy, of_g1, of_b1, ST1, XB, YB);
        else
            gnrk_kernel<2><<<8192, 256, 0, stream>>>(YTB, STRAW2, of_g3, of_b3, y, DB,
                                                     ca, cy, of_g1, of_b1, ST1, XB, YB);
    };

    for (int s = 0; s < 8; ++s) {
        const float t0 = h * (float)s;
        eval(YB, t0,            h / 6.f, 0.5f * h, 0);   // k1
        eval(XB, t0 + 0.5f * h, h / 3.f, 0.5f * h, 1);   // k2
        eval(XB, t0 + 0.5f * h, h / 3.f, h,        1);   // k3
        eval(XB, t0 + h,        h / 6.f, 0.f,      2);   // k4
    }
}